// Round 1
// baseline (163.935 us; speedup 1.0000x reference)
//
#include <hip/hip_runtime.h>
#include <hip/hip_bf16.h>
#include <math.h>

#define H    512
#define NB   16
#define LQ   64
#define LA   100
#define LAP  128
#define L2E2 2.885390081777927f   /* 2*log2(e) */

// ---------------------------------------------------------------------------
// Kernel A: projections.
//   blocks 0..127   : a1 (M=1024 rows = b*64+q), C = c1@Wa + c1^2@Waq + ba+baq
//   blocks 128..327 : q2 (M=1600 rows = b*100+a), C = c2@Wq + bq
// Both outputs pre-scaled by 2*log2(e); q2 stored transposed [b][h][a(pad 128)]
// 64x64 tile, BK=16, 256 threads, 4x4 microtile.
// ---------------------------------------------------------------------------
__global__ __launch_bounds__(256) void proj_kernel(
    const float* __restrict__ c1, const float* __restrict__ c2,
    const float* __restrict__ Wq, const float* __restrict__ bq,
    const float* __restrict__ Wa, const float* __restrict__ ba,
    const float* __restrict__ Waq, const float* __restrict__ baq,
    float* __restrict__ a1out, float* __restrict__ q2t)
{
    __shared__ __align__(16) float As[16][68];   // [k][m], stride 68 keeps 16B align + conflict-free
    __shared__ __align__(16) float Bs[16][64];   // [k][n]

    const int bid  = blockIdx.x;
    const bool isA1 = bid < 128;
    int mt, nt;
    if (isA1) { mt = bid >> 3; nt = bid & 7; }
    else      { int b2 = bid - 128; mt = b2 >> 3; nt = b2 & 7; }
    const int m0 = mt * 64, n0 = nt * 64;
    const int t  = threadIdx.x;
    const int tx = t & 15, ty = t >> 4;

    float acc[4][4];
#pragma unroll
    for (int i = 0; i < 4; ++i)
#pragma unroll
        for (int j = 0; j < 4; ++j) acc[i][j] = 0.f;

    const int am = t >> 2, ak = (t & 3) << 2;   // A-tile load coords (64 rows x 16 k)
    const int bk = t >> 4, bn = (t & 15) << 2;  // B-tile load coords (16 k x 64 n)
    const int npass = isA1 ? 2 : 1;

    for (int pass = 0; pass < npass; ++pass) {
        const float* X = isA1 ? c1 : c2;
        const float* W = isA1 ? (pass == 0 ? Wa : Waq) : Wq;
        for (int k0 = 0; k0 < H; k0 += 16) {
            float4 av = *(const float4*)(X + (size_t)(m0 + am) * H + k0 + ak);
            if (pass) { av.x *= av.x; av.y *= av.y; av.z *= av.z; av.w *= av.w; }
            float4 bv4 = *(const float4*)(W + (size_t)(k0 + bk) * H + n0 + bn);
            __syncthreads();                 // protect LDS from previous compute
            As[ak + 0][am] = av.x;
            As[ak + 1][am] = av.y;
            As[ak + 2][am] = av.z;
            As[ak + 3][am] = av.w;
            *(float4*)(&Bs[bk][bn]) = bv4;
            __syncthreads();
#pragma unroll
            for (int k = 0; k < 16; ++k) {
                float4 a4 = *(const float4*)(&As[k][ty << 2]);
                float4 b4 = *(const float4*)(&Bs[k][tx << 2]);
                float ar[4] = {a4.x, a4.y, a4.z, a4.w};
                float br[4] = {b4.x, b4.y, b4.z, b4.w};
#pragma unroll
                for (int i = 0; i < 4; ++i)
#pragma unroll
                    for (int j = 0; j < 4; ++j)
                        acc[i][j] = fmaf(ar[i], br[j], acc[i][j]);
            }
        }
    }

    if (isA1) {
        float bias[4];
#pragma unroll
        for (int j = 0; j < 4; ++j) { int n = n0 + (tx << 2) + j; bias[j] = ba[n] + baq[n]; }
#pragma unroll
        for (int i = 0; i < 4; ++i) {
            int r = m0 + (ty << 2) + i;
            float4 o;
            o.x = (acc[i][0] + bias[0]) * L2E2;
            o.y = (acc[i][1] + bias[1]) * L2E2;
            o.z = (acc[i][2] + bias[2]) * L2E2;
            o.w = (acc[i][3] + bias[3]) * L2E2;
            *(float4*)(a1out + (size_t)r * H + n0 + (tx << 2)) = o;
        }
    } else {
#pragma unroll
        for (int i = 0; i < 4; ++i) {
            int r = m0 + (ty << 2) + i;
            int b = r / 100;
            int a = r - b * 100;
#pragma unroll
            for (int j = 0; j < 4; ++j) {
                int n = n0 + (tx << 2) + j;
                q2t[(size_t)b * (H * LAP) + (size_t)n * LAP + a] =
                    (acc[i][j] + bq[n]) * L2E2;
            }
        }
    }
}

// ---------------------------------------------------------------------------
// Kernel B: score + entropy. One block per (b, qgroup-of-4). 256 threads:
// thread = (hh in {0,1}, a in [0,128)). Each thread accumulates
// R[q] = sum_{h in half} wv[h] * 1/(1+exp2(a1'[q][h]+q2'[h][a])) — no
// cross-lane reduce needed. score = bv + sum(wv) - 2*(R0+R1).
// Entropy per q handled by one wave via shuffles.
// ---------------------------------------------------------------------------
__global__ __launch_bounds__(256) void score_entropy_kernel(
    const float* __restrict__ a1, const float* __restrict__ q2t,
    const float* __restrict__ wvp, const float* __restrict__ bvp,
    float* __restrict__ out)
{
    __shared__ __align__(16) float a1s[4][H];
    __shared__ __align__(16) float wvs[H];
    __shared__ __align__(16) float part[2][LAP][4];

    const int t  = threadIdx.x;
    const int b  = blockIdx.x >> 4;
    const int qg = blockIdx.x & 15;

    for (int i = t; i < 4 * H; i += 256) {
        int q = i >> 9, h = i & (H - 1);
        a1s[q][h] = a1[(size_t)(b * LQ + (qg << 2) + q) * H + h];
    }
    for (int i = t; i < H; i += 256) wvs[i] = wvp[i];
    __syncthreads();

    const int a  = t & 127;
    const int hh = t >> 7;
    const float* q2p = q2t + (size_t)b * (H * LAP) + (size_t)(hh * 256) * LAP + a;
    const int hb = hh * 256;

    float R0 = 0.f, R1 = 0.f, R2 = 0.f, R3 = 0.f;
#pragma unroll 4
    for (int h = 0; h < 256; ++h) {
        float v = q2p[(size_t)h * LAP];
        float w = wvs[hb + h];
        float r0 = __builtin_amdgcn_rcpf(__builtin_amdgcn_exp2f(a1s[0][hb + h] + v) + 1.f);
        float r1 = __builtin_amdgcn_rcpf(__builtin_amdgcn_exp2f(a1s[1][hb + h] + v) + 1.f);
        float r2 = __builtin_amdgcn_rcpf(__builtin_amdgcn_exp2f(a1s[2][hb + h] + v) + 1.f);
        float r3 = __builtin_amdgcn_rcpf(__builtin_amdgcn_exp2f(a1s[3][hb + h] + v) + 1.f);
        R0 = fmaf(w, r0, R0);
        R1 = fmaf(w, r1, R1);
        R2 = fmaf(w, r2, R2);
        R3 = fmaf(w, r3, R3);
    }
    *(float4*)(&part[hh][a][0]) = make_float4(R0, R1, R2, R3);
    __syncthreads();

    // entropy: wave w handles local q = w
    const int l = t & 63, q = t >> 6;
    float ws = 0.f;
#pragma unroll
    for (int i = 0; i < 8; ++i) ws += wvs[l + (i << 6)];
#pragma unroll
    for (int o = 32; o; o >>= 1) ws += __shfl_xor(ws, o);

    const float bv = bvp[0];
    const float base = bv + ws;
    float sc1 = base - 2.f * (part[0][l][q] + part[1][l][q]);
    const bool act2 = l < (LA - 64);
    float sc2 = act2 ? (base - 2.f * (part[0][l + 64][q] + part[1][l + 64][q]))
                     : -INFINITY;
    float m = fmaxf(sc1, sc2);
#pragma unroll
    for (int o = 32; o; o >>= 1) m = fmaxf(m, __shfl_xor(m, o));

    const float L2E = 1.4426950408889634f;
    float e1 = __builtin_amdgcn_exp2f((sc1 - m) * L2E);
    float e2 = act2 ? __builtin_amdgcn_exp2f((sc2 - m) * L2E) : 0.f;
    float Z = e1 + e2;
    float S = e1 * sc1 + (act2 ? e2 * sc2 : 0.f);
#pragma unroll
    for (int o = 32; o; o >>= 1) {
        Z += __shfl_xor(Z, o);
        S += __shfl_xor(S, o);
    }
    if (l == 0) out[b * LQ + (qg << 2) + q] = m + logf(Z) - S / Z;
}

extern "C" void kernel_launch(void* const* d_in, const int* in_sizes, int n_in,
                              void* d_out, int out_size, void* d_ws, size_t ws_size,
                              hipStream_t stream) {
    const float* c1  = (const float*)d_in[0];
    const float* c2  = (const float*)d_in[1];
    // d_in[2] = is_user (0) — branch fixed, unused
    const float* Wq  = (const float*)d_in[3];
    const float* bq  = (const float*)d_in[4];
    const float* Wa  = (const float*)d_in[5];
    const float* ba  = (const float*)d_in[6];
    const float* Waq = (const float*)d_in[7];
    const float* baq = (const float*)d_in[8];
    const float* Wv  = (const float*)d_in[9];
    const float* bv  = (const float*)d_in[10];
    float* out = (float*)d_out;

    float* a1  = (float*)d_ws;                       // 1024*512 f32 = 2 MB
    float* q2t = a1 + (size_t)1024 * 512;            // 16*512*128 f32 = 4 MB

    proj_kernel<<<dim3(328), dim3(256), 0, stream>>>(c1, c2, Wq, bq, Wa, ba,
                                                     Waq, baq, a1, q2t);
    score_entropy_kernel<<<dim3(256), dim3(256), 0, stream>>>(a1, q2t, Wv, bv, out);
}

// Round 2
// 115.798 us; speedup vs baseline: 1.4157x; 1.4157x over previous
//
#include <hip/hip_runtime.h>
#include <math.h>

#define H    512
#define LQ   64
#define LA   100
#define LAP  128
#define L2E2 2.885390081777927f   /* 2*log2(e): exp2(a1'+q2') = e^{2x} */

using short8  = __attribute__((ext_vector_type(8))) short;
using floatx4 = __attribute__((ext_vector_type(4))) float;

__device__ __forceinline__ unsigned short f2bf(float f) {
    unsigned int u = __float_as_uint(f);
    u += 0x7fffu + ((u >> 16) & 1u);          // RNE
    return (unsigned short)(u >> 16);
}
__device__ __forceinline__ unsigned int packbf2(float a, float b) {
    return (unsigned int)f2bf(a) | ((unsigned int)f2bf(b) << 16);
}

// ---------------------------------------------------------------------------
// prep: W[k][n] fp32 -> BT[n][k] bf16 (k-contiguous = MFMA B-fragment order).
// B1T[n][0..511]=Wa, B1T[n][512..1023]=Waq ; B2T[n][0..511]=Wq.
// 192 blocks: mat = bid/64, 64 tiles of 64x64 per matrix.
// ---------------------------------------------------------------------------
__global__ __launch_bounds__(256) void prep_kernel(
    const float* __restrict__ Wq, const float* __restrict__ Wa,
    const float* __restrict__ Waq,
    unsigned short* __restrict__ B1T, unsigned short* __restrict__ B2T)
{
    __shared__ float lt[64][65];                 // +1 pad: conflict-free
    const int bid = blockIdx.x;
    const int mat = bid >> 6;                    // 0=Wa 1=Waq 2=Wq
    const int tile = bid & 63;
    const int k0 = (tile >> 3) * 64, n0 = (tile & 7) * 64;
    const float* W = (mat == 0) ? Wa : (mat == 1) ? Waq : Wq;
    const int t = threadIdx.x;
#pragma unroll
    for (int i = 0; i < 16; ++i) {
        int idx = i * 256 + t;
        int k = idx >> 6, n = idx & 63;          // lanes along n: coalesced
        lt[n][k] = W[(size_t)(k0 + k) * H + n0 + n];
    }
    __syncthreads();
    unsigned short* dst; int Kt, koff;
    if (mat == 2) { dst = B2T; Kt = 512;  koff = k0; }
    else          { dst = B1T; Kt = 1024; koff = k0 + (mat == 1 ? 512 : 0); }
#pragma unroll
    for (int i = 0; i < 8; ++i) {
        int idx = i * 256 + t;
        int n = idx >> 5, kk = (idx & 31) * 2;   // lanes along k: coalesced
        unsigned int p = packbf2(lt[n][kk], lt[n][kk + 1]);
        *(unsigned int*)(dst + (size_t)(n0 + n) * Kt + koff + kk) = p;
    }
}

// ---------------------------------------------------------------------------
// gemm: bf16 MFMA 16x16x32, BM=BN=64, BK=64, 256 thr (4 waves, each a 16-row
// strip of 4 n-tiles). LDS XOR-swizzle: elem (row, k) at row*128 +
// ((k>>3)^(row&7))*16 + (k&7)*2 -> ds_read_b128 fragments conflict-free.
//   blocks 0..127 : a1 = [c1|c1^2] @ B1T^T  (M=1024,K=1024), out *L2E2 +bias
//   blocks 128..327: q2 = c2 @ B2T^T (M=1600,K=512), out transposed [b][h][a]
// ---------------------------------------------------------------------------
__global__ __launch_bounds__(256) void gemm_kernel(
    const float* __restrict__ c1, const float* __restrict__ c2,
    const unsigned short* __restrict__ B1T, const unsigned short* __restrict__ B2T,
    const float* __restrict__ bq, const float* __restrict__ ba,
    const float* __restrict__ baq,
    float* __restrict__ a1, float* __restrict__ q2t)
{
    __shared__ __align__(16) unsigned short As[64 * 64];
    __shared__ __align__(16) unsigned short Bs[64 * 64];

    const int bid = blockIdx.x;
    const bool g1 = bid < 128;
    int mt, nt, Ktot;
    if (g1) { mt = bid >> 3; nt = bid & 7; Ktot = 1024; }
    else { int b2 = bid - 128; mt = b2 >> 3; nt = b2 & 7; Ktot = 512; }
    const int m0 = mt * 64, n0 = nt * 64;
    const unsigned short* BT = g1 ? B1T : B2T;

    const int t = threadIdx.x;
    const int w = t >> 6, lane = t & 63;
    const int q = lane >> 4, ln = lane & 15;
    const int sm = t >> 2, sc = t & 3;           // staging: row, chunk-pair

    floatx4 acc[4];
#pragma unroll
    for (int j = 0; j < 4; ++j) acc[j] = (floatx4){0.f, 0.f, 0.f, 0.f};

    for (int k0 = 0; k0 < Ktot; k0 += 64) {
        __syncthreads();
        { // stage A: fp32 global -> bf16 LDS (square on the fly for k>=512)
            const bool sq = g1 && (k0 >= 512);
            const float* X = g1 ? c1 : c2;
            const float* src = X + (size_t)(m0 + sm) * H
                                 + (k0 - (sq ? 512 : 0)) + sc * 16;
            float4 f0 = *(const float4*)(src);
            float4 f1 = *(const float4*)(src + 4);
            float4 f2 = *(const float4*)(src + 8);
            float4 f3 = *(const float4*)(src + 12);
            if (sq) {
                f0.x *= f0.x; f0.y *= f0.y; f0.z *= f0.z; f0.w *= f0.w;
                f1.x *= f1.x; f1.y *= f1.y; f1.z *= f1.z; f1.w *= f1.w;
                f2.x *= f2.x; f2.y *= f2.y; f2.z *= f2.z; f2.w *= f2.w;
                f3.x *= f3.x; f3.y *= f3.y; f3.z *= f3.z; f3.w *= f3.w;
            }
            uint4 p0, p1;
            p0.x = packbf2(f0.x, f0.y); p0.y = packbf2(f0.z, f0.w);
            p0.z = packbf2(f1.x, f1.y); p0.w = packbf2(f1.z, f1.w);
            p1.x = packbf2(f2.x, f2.y); p1.y = packbf2(f2.z, f2.w);
            p1.z = packbf2(f3.x, f3.y); p1.w = packbf2(f3.z, f3.w);
            const int c = sc * 2, sw = sm & 7;
            *(uint4*)((char*)As + sm * 128 + ((c    ) ^ sw) * 16) = p0;
            *(uint4*)((char*)As + sm * 128 + ((c + 1) ^ sw) * 16) = p1;
        }
        { // stage B: bf16 global (already [n][k]) -> LDS
            const unsigned short* src = BT + (size_t)(n0 + sm) * Ktot + k0 + sc * 16;
            uint4 q0 = *(const uint4*)(src);
            uint4 q1 = *(const uint4*)(src + 8);
            const int c = sc * 2, sw = sm & 7;
            *(uint4*)((char*)Bs + sm * 128 + ((c    ) ^ sw) * 16) = q0;
            *(uint4*)((char*)Bs + sm * 128 + ((c + 1) ^ sw) * 16) = q1;
        }
        __syncthreads();
#pragma unroll
        for (int s = 0; s < 2; ++s) {
            const int off = ((s * 4 + q) ^ (ln & 7)) * 16;
            short8 af = *(const short8*)((const char*)As + (w * 16 + ln) * 128 + off);
#pragma unroll
            for (int j = 0; j < 4; ++j) {
                short8 bf = *(const short8*)((const char*)Bs + (j * 16 + ln) * 128 + off);
                acc[j] = __builtin_amdgcn_mfma_f32_16x16x32_bf16(af, bf, acc[j], 0, 0, 0);
            }
        }
    }

    if (g1) {   // a1[R][N] = (acc + ba+baq) * 2log2e
#pragma unroll
        for (int j = 0; j < 4; ++j) {
            const int N = n0 + j * 16 + ln;
            const float bias = ba[N] + baq[N];
#pragma unroll
            for (int r = 0; r < 4; ++r) {
                const int R = m0 + w * 16 + q * 4 + r;
                a1[(size_t)R * H + N] = (acc[j][r] + bias) * L2E2;
            }
        }
    } else {    // q2t[b][N][a] = (acc + bq) * 2log2e   (R = b*100+a)
#pragma unroll
        for (int r = 0; r < 4; ++r) {
            const int R = m0 + w * 16 + q * 4 + r;
            const int bb = (R * 5243) >> 19;     // R/100 for R<1600
            const int aa = R - bb * 100;
            float* dst = q2t + (size_t)bb * (H * LAP) + aa;
#pragma unroll
            for (int j = 0; j < 4; ++j) {
                const int N = n0 + j * 16 + ln;
                dst[(size_t)N * LAP] = (acc[j][r] + bq[N]) * L2E2;
            }
        }
    }
}

// ---------------------------------------------------------------------------
// score+entropy: block = (b, q-group of 4), 1024 threads = (hh in [0,8), a in
// [0,128)). Thread sums R[q] = sum_{h in 64-chunk} wv[h]/(1+exp2(a1'+q2'));
// score = bv + sum(wv) - 2*sum_hh R. Entropy: wave per q, shuffle-reduce.
// ---------------------------------------------------------------------------
__global__ __launch_bounds__(1024) void score_entropy_kernel(
    const float* __restrict__ a1, const float* __restrict__ q2t,
    const float* __restrict__ wvp, const float* __restrict__ bvp,
    float* __restrict__ out)
{
    __shared__ __align__(16) float a1s[4][H];
    __shared__ __align__(16) float wvs[H];
    __shared__ __align__(16) float part[8][LAP][4];

    const int t  = threadIdx.x;
    const int b  = blockIdx.x >> 4;
    const int qg = blockIdx.x & 15;

    for (int i = t; i < 4 * H; i += 1024) {
        int q = i >> 9, h = i & (H - 1);
        a1s[q][h] = a1[(size_t)(b * LQ + (qg << 2) + q) * H + h];
    }
    if (t < H) wvs[t] = wvp[t];
    __syncthreads();

    const int a  = t & 127;
    const int hh = t >> 7;
    const int hb = hh * 64;
    const float* q2p = q2t + (size_t)b * (H * LAP) + (size_t)hb * LAP + a;

    float R0 = 0.f, R1 = 0.f, R2 = 0.f, R3 = 0.f;
#pragma unroll 8
    for (int h = 0; h < 64; ++h) {
        float v = q2p[(size_t)h * LAP];
        float w = wvs[hb + h];
        float r0 = __builtin_amdgcn_rcpf(__builtin_amdgcn_exp2f(a1s[0][hb + h] + v) + 1.f);
        float r1 = __builtin_amdgcn_rcpf(__builtin_amdgcn_exp2f(a1s[1][hb + h] + v) + 1.f);
        float r2 = __builtin_amdgcn_rcpf(__builtin_amdgcn_exp2f(a1s[2][hb + h] + v) + 1.f);
        float r3 = __builtin_amdgcn_rcpf(__builtin_amdgcn_exp2f(a1s[3][hb + h] + v) + 1.f);
        R0 = fmaf(w, r0, R0);
        R1 = fmaf(w, r1, R1);
        R2 = fmaf(w, r2, R2);
        R3 = fmaf(w, r3, R3);
    }
    *(float4*)(&part[hh][a][0]) = make_float4(R0, R1, R2, R3);
    __syncthreads();

    if (t < 256) {
        const int l = t & 63, q = t >> 6;        // wave q handles local q
        float ws = 0.f;
#pragma unroll
        for (int i = 0; i < 8; ++i) ws += wvs[l + (i << 6)];
#pragma unroll
        for (int o = 32; o; o >>= 1) ws += __shfl_xor(ws, o);

        const float base = bvp[0] + ws;
        float s1 = 0.f, s2 = 0.f;
#pragma unroll
        for (int i = 0; i < 8; ++i) s1 += part[i][l][q];
        const bool act2 = l < (LA - 64);
        if (act2) {
#pragma unroll
            for (int i = 0; i < 8; ++i) s2 += part[i][l + 64][q];
        }
        float sc1 = base - 2.f * s1;
        float sc2 = act2 ? (base - 2.f * s2) : -INFINITY;
        float m = fmaxf(sc1, sc2);
#pragma unroll
        for (int o = 32; o; o >>= 1) m = fmaxf(m, __shfl_xor(m, o));

        const float L2E = 1.4426950408889634f;
        float e1 = __builtin_amdgcn_exp2f((sc1 - m) * L2E);
        float e2 = act2 ? __builtin_amdgcn_exp2f((sc2 - m) * L2E) : 0.f;
        float Z = e1 + e2;
        float S = e1 * sc1 + (act2 ? e2 * sc2 : 0.f);
#pragma unroll
        for (int o = 32; o; o >>= 1) {
            Z += __shfl_xor(Z, o);
            S += __shfl_xor(S, o);
        }
        if (l == 0) out[b * LQ + (qg << 2) + q] = m + logf(Z) - S / Z;
    }
}

extern "C" void kernel_launch(void* const* d_in, const int* in_sizes, int n_in,
                              void* d_out, int out_size, void* d_ws, size_t ws_size,
                              hipStream_t stream) {
    const float* c1  = (const float*)d_in[0];
    const float* c2  = (const float*)d_in[1];
    const float* Wq  = (const float*)d_in[3];
    const float* bq  = (const float*)d_in[4];
    const float* Wa  = (const float*)d_in[5];
    const float* ba  = (const float*)d_in[6];
    const float* Waq = (const float*)d_in[7];
    const float* baq = (const float*)d_in[8];
    const float* Wv  = (const float*)d_in[9];
    const float* bv  = (const float*)d_in[10];
    float* out = (float*)d_out;

    float* a1  = (float*)d_ws;                                   // 2 MB
    float* q2t = a1 + (size_t)1024 * 512;                        // 4 MB
    unsigned short* B1T = (unsigned short*)(q2t + (size_t)16 * 512 * 128); // 1 MB
    unsigned short* B2T = B1T + (size_t)512 * 1024;              // 0.5 MB

    prep_kernel<<<dim3(192), dim3(256), 0, stream>>>(Wq, Wa, Waq, B1T, B2T);
    gemm_kernel<<<dim3(328), dim3(256), 0, stream>>>(c1, c2, B1T, B2T,
                                                     bq, ba, baq, a1, q2t);
    score_entropy_kernel<<<dim3(256), dim3(1024), 0, stream>>>(a1, q2t, Wv, bv, out);
}

// Round 3
// 105.873 us; speedup vs baseline: 1.5484x; 1.0937x over previous
//
#include <hip/hip_runtime.h>
#include <math.h>

#define H    512
#define LQ   64
#define LA   100
#define LAP  128
#define L2E2 2.885390081777927f   /* 2*log2(e): exp2(a1'+q2') = e^{2x} */

using short8  = __attribute__((ext_vector_type(8))) short;
using floatx4 = __attribute__((ext_vector_type(4))) float;

__device__ __forceinline__ unsigned short f2bf(float f) {
    unsigned int u = __float_as_uint(f);
    u += 0x7fffu + ((u >> 16) & 1u);          // RNE
    return (unsigned short)(u >> 16);
}
__device__ __forceinline__ unsigned int packbf2(float a, float b) {
    return (unsigned int)f2bf(a) | ((unsigned int)f2bf(b) << 16);
}

// async 16B global -> LDS (DMA, no VGPR round-trip). lptr must be
// wave-uniform; HW adds lane*16. AS(3) ptr = low 32 bits of generic LDS ptr.
__device__ __forceinline__ void async_cp16(const void* g, void* l) {
    __builtin_amdgcn_global_load_lds(
        (const __attribute__((address_space(1))) unsigned int*)(uintptr_t)g,
        (__attribute__((address_space(3))) unsigned int*)(unsigned int)(uintptr_t)l,
        16, 0, 0);
}

// ---------------------------------------------------------------------------
// prep: build pre-swizzled bf16 8KB tiles (64 rows x 64 k) in global memory.
// Element (r, k) lives at byte  r*128 + (((k>>3) ^ (r&7))*16) + (k&7)*2,
// i.e. the EXACT image global_load_lds produces in LDS -> K-loop is pure DMA.
//   blocks 0..127  : A1 tiles (mt 0..15, kc 0..7) from c1; kc+8 tile = c1^2
//   blocks 128..327: A2 tiles (mt 0..24, kc 0..7) from c2 (1600 = 25*64 rows)
//   blocks 328..455: B1 tiles (nt 0..7, kc 0..15): W^T of Wa (kc<8) / Waq
//   blocks 456..519: B2 tiles (nt 0..7, kc 0..7):  W^T of Wq
// ---------------------------------------------------------------------------
__global__ __launch_bounds__(256) void prep_kernel(
    const float* __restrict__ c1, const float* __restrict__ c2,
    const float* __restrict__ Wq, const float* __restrict__ Wa,
    const float* __restrict__ Waq,
    unsigned short* __restrict__ A1sw, unsigned short* __restrict__ A2sw,
    unsigned short* __restrict__ B1sw, unsigned short* __restrict__ B2sw)
{
    __shared__ __align__(16) float lt[64][68];   // B-transpose scratch
    const int bid = blockIdx.x, t = threadIdx.x;

    if (bid < 328) {            // ---- A path: row-major read, swizzled write
        const bool isA1 = bid < 128;
        int mt, kc; const float* X;
        if (isA1) { mt = bid >> 3; kc = bid & 7; X = c1; }
        else      { int b2 = bid - 128; mt = b2 >> 3; kc = b2 & 7; X = c2; }
#pragma unroll
        for (int i = 0; i < 4; ++i) {
            int idx = i * 256 + t;
            int r = idx >> 4, c4 = idx & 15;
            float4 v = *(const float4*)(X + (size_t)(mt * 64 + r) * H + kc * 64 + c4 * 4);
            int bytepos = r * 128 + (((c4 >> 1) ^ (r & 7)) * 16) + (c4 & 1) * 8;
            if (isA1) {
                unsigned short* t1 = A1sw + (size_t)(mt * 16 + kc) * 4096;
                *(uint2*)((char*)t1 + bytepos) = make_uint2(packbf2(v.x, v.y), packbf2(v.z, v.w));
                unsigned short* t2 = A1sw + (size_t)(mt * 16 + kc + 8) * 4096;
                *(uint2*)((char*)t2 + bytepos) =
                    make_uint2(packbf2(v.x * v.x, v.y * v.y), packbf2(v.z * v.z, v.w * v.w));
            } else {
                unsigned short* t1 = A2sw + (size_t)(mt * 8 + kc) * 4096;
                *(uint2*)((char*)t1 + bytepos) = make_uint2(packbf2(v.x, v.y), packbf2(v.z, v.w));
            }
        }
    } else {                    // ---- B path: transpose W[k][n] -> [n][k] tiles
        int b3 = bid - 328;
        const bool isB1 = b3 < 128;
        int nt, kc; const float* W; int k0;
        if (isB1) { nt = b3 >> 4; kc = b3 & 15; W = (kc < 8) ? Wa : Waq; k0 = (kc & 7) * 64; }
        else      { int b4 = b3 - 128; nt = b4 >> 3; kc = b4 & 7; W = Wq; k0 = kc * 64; }
        const int n0 = nt * 64;
#pragma unroll
        for (int i = 0; i < 4; ++i) {
            int idx = i * 256 + t;
            int k = idx >> 4, n4 = idx & 15;
            float4 v = *(const float4*)(W + (size_t)(k0 + k) * H + n0 + n4 * 4);
            lt[n4 * 4 + 0][k] = v.x;
            lt[n4 * 4 + 1][k] = v.y;
            lt[n4 * 4 + 2][k] = v.z;
            lt[n4 * 4 + 3][k] = v.w;
        }
        __syncthreads();
#pragma unroll
        for (int i = 0; i < 4; ++i) {
            int idx = i * 256 + t;
            int r = idx >> 4, c4 = idx & 15;
            float4 v = *(const float4*)&lt[r][c4 * 4];
            int bytepos = r * 128 + (((c4 >> 1) ^ (r & 7)) * 16) + (c4 & 1) * 8;
            unsigned short* tile = isB1 ? B1sw + (size_t)(nt * 16 + kc) * 4096
                                        : B2sw + (size_t)(nt * 8 + kc) * 4096;
            *(uint2*)((char*)tile + bytepos) = make_uint2(packbf2(v.x, v.y), packbf2(v.z, v.w));
        }
    }
}

// ---------------------------------------------------------------------------
// gemm: bf16 MFMA 16x16x32, BM=BN=64, BK=64, 256 thr. Double-buffered LDS;
// K-loop = 4 global_load_lds (prefetch) + 10 ds_read_b128 + 8 MFMA + barrier
// per wave — zero staging VALU. XOR-swizzle baked into the global tiles.
//   blocks 0..127 : a1 = [c1|c1^2] @ [Wa;Waq]^T (K=1024), out = (acc+bias)*L2E2
//   blocks 128..327: q2 = c2 @ Wq^T (K=512), out transposed [b][h][a(pad128)]
// ---------------------------------------------------------------------------
__global__ __launch_bounds__(256) void gemm_kernel(
    const unsigned short* __restrict__ A1sw, const unsigned short* __restrict__ A2sw,
    const unsigned short* __restrict__ B1sw, const unsigned short* __restrict__ B2sw,
    const float* __restrict__ bq, const float* __restrict__ ba,
    const float* __restrict__ baq,
    float* __restrict__ a1, float* __restrict__ q2t)
{
    __shared__ __align__(16) unsigned short As[2][4096];
    __shared__ __align__(16) unsigned short Bs[2][4096];

    const int bid = blockIdx.x;
    const bool g1 = bid < 128;
    int mt, nt, nk;
    const unsigned short *Abase, *Bbase;
    if (g1) {
        mt = bid >> 3; nt = bid & 7; nk = 16;
        Abase = A1sw + (size_t)(mt * 16) * 4096;
        Bbase = B1sw + (size_t)(nt * 16) * 4096;
    } else {
        int b2 = bid - 128; mt = b2 >> 3; nt = b2 & 7; nk = 8;
        Abase = A2sw + (size_t)(mt * 8) * 4096;
        Bbase = B2sw + (size_t)(nt * 8) * 4096;
    }
    const int m0 = mt * 64, n0 = nt * 64;

    const int t = threadIdx.x;
    const int w = t >> 6, lane = t & 63;
    const int q = lane >> 4, ln = lane & 15;
    const int goff = w * 1024 + lane * 8;   // per-lane global elem offset
    const int loff = w * 1024;              // wave-uniform LDS elem offset

    floatx4 acc[4];
#pragma unroll
    for (int j = 0; j < 4; ++j) acc[j] = (floatx4){0.f, 0.f, 0.f, 0.f};

    // prologue: stage kc=0 into buffer 0
    {
        const unsigned short* ga = Abase;
        const unsigned short* gb = Bbase;
        async_cp16(ga + goff,       &As[0][loff]);
        async_cp16(ga + goff + 512, &As[0][loff + 512]);
        async_cp16(gb + goff,       &Bs[0][loff]);
        async_cp16(gb + goff + 512, &Bs[0][loff + 512]);
    }
    __syncthreads();

    int buf = 0;
    for (int kc = 0; kc < nk; ++kc) {
        if (kc + 1 < nk) {      // prefetch next tile into other buffer (async)
            const unsigned short* ga = Abase + (size_t)(kc + 1) * 4096;
            const unsigned short* gb = Bbase + (size_t)(kc + 1) * 4096;
            async_cp16(ga + goff,       &As[buf ^ 1][loff]);
            async_cp16(ga + goff + 512, &As[buf ^ 1][loff + 512]);
            async_cp16(gb + goff,       &Bs[buf ^ 1][loff]);
            async_cp16(gb + goff + 512, &Bs[buf ^ 1][loff + 512]);
        }
#pragma unroll
        for (int s = 0; s < 2; ++s) {
            const int off = ((s * 4 + q) ^ (ln & 7)) * 16;
            short8 af = *(const short8*)((const char*)&As[buf][0] + (w * 16 + ln) * 128 + off);
#pragma unroll
            for (int j = 0; j < 4; ++j) {
                short8 bf = *(const short8*)((const char*)&Bs[buf][0] + (j * 16 + ln) * 128 + off);
                acc[j] = __builtin_amdgcn_mfma_f32_16x16x32_bf16(af, bf, acc[j], 0, 0, 0);
            }
        }
        __syncthreads();        // drains prefetch (vmcnt0) + aligns waves
        buf ^= 1;
    }

    if (g1) {   // a1[R][N] = (acc + ba+baq) * 2log2e
#pragma unroll
        for (int j = 0; j < 4; ++j) {
            const int N = n0 + j * 16 + ln;
            const float bias = ba[N] + baq[N];
#pragma unroll
            for (int r = 0; r < 4; ++r) {
                const int R = m0 + w * 16 + q * 4 + r;
                a1[(size_t)R * H + N] = (acc[j][r] + bias) * L2E2;
            }
        }
    } else {    // q2t[b][N][a] = (acc + bq) * 2log2e   (R = b*100+a)
#pragma unroll
        for (int r = 0; r < 4; ++r) {
            const int R = m0 + w * 16 + q * 4 + r;
            const int bb = (R * 5243) >> 19;     // R/100 for R<1600
            const int aa = R - bb * 100;
            float* dst = q2t + (size_t)bb * (H * LAP) + aa;
#pragma unroll
            for (int j = 0; j < 4; ++j) {
                const int N = n0 + j * 16 + ln;
                dst[(size_t)N * LAP] = (acc[j][r] + bq[N]) * L2E2;
            }
        }
    }
}

// ---------------------------------------------------------------------------
// score+entropy: block = (b, q-group of 4), 1024 threads = (hh in [0,8), a in
// [0,128)). 4 h per step: float4 LDS reads (b128 broadcast) cut LDS issue 4x;
// loop is transcendental-bound (2 trans/element). score = bv + sum(wv) - 2*R.
// ---------------------------------------------------------------------------
__global__ __launch_bounds__(1024) void score_entropy_kernel(
    const float* __restrict__ a1, const float* __restrict__ q2t,
    const float* __restrict__ wvp, const float* __restrict__ bvp,
    float* __restrict__ out)
{
    __shared__ __align__(16) float a1s[4][H];
    __shared__ __align__(16) float wvs[H];
    __shared__ __align__(16) float part[8][LAP][4];

    const int t  = threadIdx.x;
    const int b  = blockIdx.x >> 4;
    const int qg = blockIdx.x & 15;

    for (int i = t; i < 4 * H; i += 1024) {
        int q = i >> 9, h = i & (H - 1);
        a1s[q][h] = a1[(size_t)(b * LQ + (qg << 2) + q) * H + h];
    }
    if (t < H) wvs[t] = wvp[t];
    __syncthreads();

    const int a  = t & 127;
    const int hh = t >> 7;
    const int hb = hh * 64;
    const float* q2p = q2t + (size_t)b * (H * LAP) + (size_t)hb * LAP + a;

    float R0 = 0.f, R1 = 0.f, R2 = 0.f, R3 = 0.f;
#define TERM(Rq, Aq, vv, ww) \
    Rq = fmaf(ww, __builtin_amdgcn_rcpf(__builtin_amdgcn_exp2f((Aq) + (vv)) + 1.f), Rq)
#pragma unroll 4
    for (int i = 0; i < 16; ++i) {
        const int h4 = i * 4;
        float4 wv4 = *(const float4*)&wvs[hb + h4];
        float4 A0 = *(const float4*)&a1s[0][hb + h4];
        float4 A1 = *(const float4*)&a1s[1][hb + h4];
        float4 A2 = *(const float4*)&a1s[2][hb + h4];
        float4 A3 = *(const float4*)&a1s[3][hb + h4];
        float v0 = q2p[(size_t)(h4 + 0) * LAP];
        float v1 = q2p[(size_t)(h4 + 1) * LAP];
        float v2 = q2p[(size_t)(h4 + 2) * LAP];
        float v3 = q2p[(size_t)(h4 + 3) * LAP];
        TERM(R0, A0.x, v0, wv4.x); TERM(R0, A0.y, v1, wv4.y);
        TERM(R0, A0.z, v2, wv4.z); TERM(R0, A0.w, v3, wv4.w);
        TERM(R1, A1.x, v0, wv4.x); TERM(R1, A1.y, v1, wv4.y);
        TERM(R1, A1.z, v2, wv4.z); TERM(R1, A1.w, v3, wv4.w);
        TERM(R2, A2.x, v0, wv4.x); TERM(R2, A2.y, v1, wv4.y);
        TERM(R2, A2.z, v2, wv4.z); TERM(R2, A2.w, v3, wv4.w);
        TERM(R3, A3.x, v0, wv4.x); TERM(R3, A3.y, v1, wv4.y);
        TERM(R3, A3.z, v2, wv4.z); TERM(R3, A3.w, v3, wv4.w);
    }
#undef TERM
    *(float4*)(&part[hh][a][0]) = make_float4(R0, R1, R2, R3);
    __syncthreads();

    if (t < 256) {
        const int l = t & 63, q = t >> 6;        // wave q handles local q
        float ws = 0.f;
#pragma unroll
        for (int i = 0; i < 8; ++i) ws += wvs[l + (i << 6)];
#pragma unroll
        for (int o = 32; o; o >>= 1) ws += __shfl_xor(ws, o);

        const float base = bvp[0] + ws;
        float s1 = 0.f, s2 = 0.f;
#pragma unroll
        for (int i = 0; i < 8; ++i) s1 += part[i][l][q];
        const bool act2 = l < (LA - 64);
        if (act2) {
#pragma unroll
            for (int i = 0; i < 8; ++i) s2 += part[i][l + 64][q];
        }
        float sc1 = base - 2.f * s1;
        float sc2 = act2 ? (base - 2.f * s2) : -INFINITY;
        float m = fmaxf(sc1, sc2);
#pragma unroll
        for (int o = 32; o; o >>= 1) m = fmaxf(m, __shfl_xor(m, o));

        const float L2E = 1.4426950408889634f;
        float e1 = __builtin_amdgcn_exp2f((sc1 - m) * L2E);
        float e2 = act2 ? __builtin_amdgcn_exp2f((sc2 - m) * L2E) : 0.f;
        float Z = e1 + e2;
        float S = e1 * sc1 + (act2 ? e2 * sc2 : 0.f);
#pragma unroll
        for (int o = 32; o; o >>= 1) {
            Z += __shfl_xor(Z, o);
            S += __shfl_xor(S, o);
        }
        if (l == 0) out[b * LQ + (qg << 2) + q] = m + logf(Z) - S / Z;
    }
}

extern "C" void kernel_launch(void* const* d_in, const int* in_sizes, int n_in,
                              void* d_out, int out_size, void* d_ws, size_t ws_size,
                              hipStream_t stream) {
    const float* c1  = (const float*)d_in[0];
    const float* c2  = (const float*)d_in[1];
    const float* Wq  = (const float*)d_in[3];
    const float* bq  = (const float*)d_in[4];
    const float* Wa  = (const float*)d_in[5];
    const float* ba  = (const float*)d_in[6];
    const float* Waq = (const float*)d_in[7];
    const float* baq = (const float*)d_in[8];
    const float* Wv  = (const float*)d_in[9];
    const float* bv  = (const float*)d_in[10];
    float* out = (float*)d_out;

    float* a1  = (float*)d_ws;                                    // 2 MB
    float* q2t = a1 + (size_t)1024 * 512;                         // 4 MB
    unsigned short* A1sw = (unsigned short*)(q2t + (size_t)16 * 512 * 128);
    unsigned short* A2sw = A1sw + (size_t)16 * 16 * 4096;         // 2 MB
    unsigned short* B1sw = A2sw + (size_t)25 * 8 * 4096;          // 1.6 MB
    unsigned short* B2sw = B1sw + (size_t)8 * 16 * 4096;          // 1 MB

    prep_kernel<<<dim3(520), dim3(256), 0, stream>>>(c1, c2, Wq, Wa, Waq,
                                                     A1sw, A2sw, B1sw, B2sw);
    gemm_kernel<<<dim3(328), dim3(256), 0, stream>>>(A1sw, A2sw, B1sw, B2sw,
                                                     bq, ba, baq, a1, q2t);
    score_entropy_kernel<<<dim3(256), dim3(1024), 0, stream>>>(a1, q2t, Wv, bv, out);
}